// Round 2
// baseline (207.232 us; speedup 1.0000x reference)
//
#include <hip/hip_runtime.h>

// One-level separable wavelet filterbank (maxflat), periodic extension.
// x: [8,3,1024,1024] f32 -> out: [4, 8,3,512,512] f32 (LL, LH, HL, HH)
//
// Round 2: no input staging tile. Row filter reads its 7 taps straight from
// global (overlapping windows -> L1 hits), writes L/H rows to LDS; one
// barrier; column filter + downsample reads LDS stride-1 and stores float2.
// LDS 18.8 KB -> 8 blocks/CU (32 waves = 100% occupancy).

constexpr int H = 1024, W = 1024;
constexpr int NIMG = 24;            // 8*3
constexpr int HOUT = 512, WOUT = 512;
constexpr int TO = 32;              // output tile edge
constexpr int RIN = 69;             // input rows needed: 2*0-4 .. 2*31+2
constexpr int PAD = 34;             // even pad: float2-aligned, banks shift 2/row

__global__ __launch_bounds__(256)
void wfb_kernel(const float* __restrict__ x, float* __restrict__ out) {
    __shared__ float s_L[RIN][PAD];     // row-lowpass at even cols
    __shared__ float s_H[RIN][PAD];     // row-highpass at even cols

    // h (len 5, ext 2) and h1 (len 7, ext 4), exact maxflat values
    const float h0c[5] = {0.125f, 0.35355339059327373f, 1.25f,
                          0.35355339059327373f, 0.125f};
    const float h1c[7] = {0.025888347648318447f,  0.07322330470336313f,
                          -0.06878156646177083f, -0.8535533905932737f,
                          -0.06878156646177083f,  0.07322330470336313f,
                          0.025888347648318447f};

    const int tid = threadIdx.x;
    const int img = blockIdx.z;
    const int r0 = blockIdx.y * TO;   // output-row offset
    const int c0 = blockIdx.x * TO;   // output-col offset
    const float* __restrict__ xin = x + (size_t)img * H * W;
    const int rbase = 2 * r0 - 4;
    const int cbase = 2 * c0 - 4;

    // ---- phase 1: horizontal L/H at even output cols, direct from global ----
    // item (r, j): input row rbase+r, taps at cols cbase + 2j + {0..6}
    for (int m = tid; m < RIN * TO; m += 256) {
        int r = m >> 5;
        int j = m & 31;
        int gr = (rbase + r) & (H - 1);         // periodic (handles negatives)
        const float* __restrict__ rowp = xin + (size_t)gr * W;
        int b = cbase + 2 * j;
        float v0 = rowp[(b + 0) & (W - 1)];
        float v1 = rowp[(b + 1) & (W - 1)];
        float v2 = rowp[(b + 2) & (W - 1)];
        float v3 = rowp[(b + 3) & (W - 1)];
        float v4 = rowp[(b + 4) & (W - 1)];
        float v5 = rowp[(b + 5) & (W - 1)];
        float v6 = rowp[(b + 6) & (W - 1)];
        s_L[r][j] = h0c[0]*v2 + h0c[1]*v3 + h0c[2]*v4 + h0c[3]*v5 + h0c[4]*v6;
        s_H[r][j] = h1c[0]*v0 + h1c[1]*v1 + h1c[2]*v2 + h1c[3]*v3
                  + h1c[4]*v4 + h1c[5]*v5 + h1c[6]*v6;
    }
    __syncthreads();

    // ---- phase 2: vertical filter at even rows; write 4 subbands (float2) ----
    constexpr size_t SB = (size_t)NIMG * HOUT * WOUT;  // per-subband stride
    float* __restrict__ o = out + (size_t)img * HOUT * WOUT;
    for (int m = tid; m < TO * (TO / 2); m += 256) {   // 512 items, 2 iters
        int i  = m >> 4;
        int jj = (m & 15) * 2;
        float LLx = 0.f, LLy = 0.f, HLx = 0.f, HLy = 0.f;
        float LHx = 0.f, LHy = 0.f, HHx = 0.f, HHy = 0.f;
        #pragma unroll
        for (int k = 0; k < 5; ++k) {
            float a0 = s_L[2*i + 2 + k][jj], a1 = s_L[2*i + 2 + k][jj + 1];
            float b0 = s_H[2*i + 2 + k][jj], b1 = s_H[2*i + 2 + k][jj + 1];
            LLx += h0c[k] * a0;  LLy += h0c[k] * a1;
            HLx += h0c[k] * b0;  HLy += h0c[k] * b1;
        }
        #pragma unroll
        for (int k = 0; k < 7; ++k) {
            float a0 = s_L[2*i + k][jj], a1 = s_L[2*i + k][jj + 1];
            float b0 = s_H[2*i + k][jj], b1 = s_H[2*i + k][jj + 1];
            LHx += h1c[k] * a0;  LHy += h1c[k] * a1;
            HHx += h1c[k] * b0;  HHy += h1c[k] * b1;
        }
        size_t off = (size_t)(r0 + i) * WOUT + (c0 + jj);
        *(float2*)(o + 0 * SB + off) = make_float2(LLx, LLy);
        *(float2*)(o + 1 * SB + off) = make_float2(LHx, LHy);
        *(float2*)(o + 2 * SB + off) = make_float2(HLx, HLy);
        *(float2*)(o + 3 * SB + off) = make_float2(HHx, HHy);
    }
}

extern "C" void kernel_launch(void* const* d_in, const int* in_sizes, int n_in,
                              void* d_out, int out_size, void* d_ws, size_t ws_size,
                              hipStream_t stream) {
    const float* x = (const float*)d_in[0];
    float* out = (float*)d_out;
    dim3 grid(WOUT / TO, HOUT / TO, NIMG);   // 16 x 16 x 24
    wfb_kernel<<<grid, dim3(256), 0, stream>>>(x, out);
}

// Round 3
// 182.315 us; speedup vs baseline: 1.1367x; 1.1367x over previous
//
#include <hip/hip_runtime.h>

// One-level separable wavelet filterbank (maxflat), periodic extension.
// x: [8,3,1024,1024] f32 -> out: [4, 8,3,512,512] f32 (LL, LH, HL, HH)
//
// Round 3: phase 1 loads 6 aligned float4 (24 contiguous floats) per item
// and computes 8 row-filter outputs from registers (no stride-2 scalar
// loads). LDS holds only L/H intermediates (19.4 KB). Phase 2: one float4
// column-filter item per thread, float4 LDS reads, dwordx4 stores.

constexpr int H = 1024, W = 1024;
constexpr int NIMG = 24;            // 8*3
constexpr int HOUT = 512, WOUT = 512;
constexpr int TO = 32;              // output tile edge
constexpr int RIN = 69;             // input rows needed: 2*0-4 .. 2*31+2
constexpr int PAD = 36;             // keeps rows 16B-aligned; 4-bank shift/row

__global__ __launch_bounds__(256)
void wfb_kernel(const float* __restrict__ x, float* __restrict__ out) {
    __shared__ float s_L[RIN][PAD];     // row-lowpass at even cols
    __shared__ float s_H[RIN][PAD];     // row-highpass at even cols

    // h (len 5, ext 2) and h1 (len 7, ext 4), exact maxflat values
    const float h0c[5] = {0.125f, 0.35355339059327373f, 1.25f,
                          0.35355339059327373f, 0.125f};
    const float h1c[7] = {0.025888347648318447f,  0.07322330470336313f,
                          -0.06878156646177083f, -0.8535533905932737f,
                          -0.06878156646177083f,  0.07322330470336313f,
                          0.025888347648318447f};

    const int tid = threadIdx.x;
    const int img = blockIdx.z;
    const int r0 = blockIdx.y * TO;   // output-row offset
    const int c0 = blockIdx.x * TO;   // output-col offset
    const float* __restrict__ xin = x + (size_t)img * H * W;
    const int rbase = 2 * r0 - 4;
    const int cbase = 2 * c0 - 4;     // multiple of 4 -> float4-aligned

    // ---- phase 1: 8 horizontal L/H outputs per item from 6 float4 loads ----
    // item (r, g): input row rbase+r, output cols j0=8g..8g+7,
    // taps at global cols b0 + [0..20], b0 = cbase + 16g.
    for (int m = tid; m < RIN * 4; m += 256) {
        int r = m >> 2;
        int g = m & 3;
        int gr = (rbase + r) & (H - 1);         // periodic rows
        const float* __restrict__ rowp = xin + (size_t)gr * W;
        int b0 = cbase + 16 * g;
        float v[24];
        #pragma unroll
        for (int t = 0; t < 6; ++t) {
            int gc = (b0 + 4 * t) & (W - 1);    // wrap preserves 16B alignment
            float4 f = *(const float4*)(rowp + gc);
            v[4*t + 0] = f.x; v[4*t + 1] = f.y;
            v[4*t + 2] = f.z; v[4*t + 3] = f.w;
        }
        float Lo[8], Ho[8];
        #pragma unroll
        for (int u = 0; u < 8; ++u) {
            const float* p = v + 2 * u;
            Lo[u] = h0c[0]*p[2] + h0c[1]*p[3] + h0c[2]*p[4]
                  + h0c[3]*p[5] + h0c[4]*p[6];
            Ho[u] = h1c[0]*p[0] + h1c[1]*p[1] + h1c[2]*p[2] + h1c[3]*p[3]
                  + h1c[4]*p[4] + h1c[5]*p[5] + h1c[6]*p[6];
        }
        int j0 = 8 * g;
        *(float4*)&s_L[r][j0]     = make_float4(Lo[0], Lo[1], Lo[2], Lo[3]);
        *(float4*)&s_L[r][j0 + 4] = make_float4(Lo[4], Lo[5], Lo[6], Lo[7]);
        *(float4*)&s_H[r][j0]     = make_float4(Ho[0], Ho[1], Ho[2], Ho[3]);
        *(float4*)&s_H[r][j0 + 4] = make_float4(Ho[4], Ho[5], Ho[6], Ho[7]);
    }
    __syncthreads();

    // ---- phase 2: vertical filter at even rows; float4 per thread ----
    constexpr size_t SB = (size_t)NIMG * HOUT * WOUT;  // per-subband stride
    float* __restrict__ o = out + (size_t)img * HOUT * WOUT;
    {
        int i  = tid >> 3;          // 0..31 output row in tile
        int jj = (tid & 7) * 4;     // 0,4,...,28 output col in tile
        float LLx=0,LLy=0,LLz=0,LLw=0, HLx=0,HLy=0,HLz=0,HLw=0;
        float LHx=0,LHy=0,LHz=0,LHw=0, HHx=0,HHy=0,HHz=0,HHw=0;
        #pragma unroll
        for (int k = 0; k < 5; ++k) {
            float4 a = *(const float4*)&s_L[2*i + 2 + k][jj];
            float4 b = *(const float4*)&s_H[2*i + 2 + k][jj];
            LLx += h0c[k]*a.x; LLy += h0c[k]*a.y; LLz += h0c[k]*a.z; LLw += h0c[k]*a.w;
            HLx += h0c[k]*b.x; HLy += h0c[k]*b.y; HLz += h0c[k]*b.z; HLw += h0c[k]*b.w;
        }
        #pragma unroll
        for (int k = 0; k < 7; ++k) {
            float4 a = *(const float4*)&s_L[2*i + k][jj];
            float4 b = *(const float4*)&s_H[2*i + k][jj];
            LHx += h1c[k]*a.x; LHy += h1c[k]*a.y; LHz += h1c[k]*a.z; LHw += h1c[k]*a.w;
            HHx += h1c[k]*b.x; HHy += h1c[k]*b.y; HHz += h1c[k]*b.z; HHw += h1c[k]*b.w;
        }
        size_t off = (size_t)(r0 + i) * WOUT + (c0 + jj);
        *(float4*)(o + 0 * SB + off) = make_float4(LLx, LLy, LLz, LLw);
        *(float4*)(o + 1 * SB + off) = make_float4(LHx, LHy, LHz, LHw);
        *(float4*)(o + 2 * SB + off) = make_float4(HLx, HLy, HLz, HLw);
        *(float4*)(o + 3 * SB + off) = make_float4(HHx, HHy, HHz, HHw);
    }
}

extern "C" void kernel_launch(void* const* d_in, const int* in_sizes, int n_in,
                              void* d_out, int out_size, void* d_ws, size_t ws_size,
                              hipStream_t stream) {
    const float* x = (const float*)d_in[0];
    float* out = (float*)d_out;
    dim3 grid(WOUT / TO, HOUT / TO, NIMG);   // 16 x 16 x 24
    wfb_kernel<<<grid, dim3(256), 0, stream>>>(x, out);
}